// Round 4
// baseline (3104.665 us; speedup 1.0000x reference)
//
#include <hip/hip_runtime.h>
#include <cstdint>
#include <cstddef>

// Problem dims
#define B_   64
#define S_   512
#define E_   300
#define EP   320     // E padded to multiple of 32 (zero pad)
#define H_   512
#define G3   1536    // packed gates: [i(512), g(512), o(512)] (f-gate unused: c_prev==0)
#define NWGS 64      // scan grid: 4 groups x 16 WGs

typedef float  f32x4 __attribute__((ext_vector_type(4)));
typedef short  s16x8 __attribute__((ext_vector_type(8)));
typedef unsigned long long u64;

__device__ __forceinline__ unsigned short f2bf(float f) {
  union { float f; unsigned u; } v; v.f = f;
  return (unsigned short)((v.u + 0x7fffu + ((v.u >> 16) & 1u)) >> 16);  // RNE
}
__device__ __forceinline__ float bf2f(unsigned short s) {
  union { unsigned u; float f; } v; v.u = ((unsigned)s) << 16;
  return v.f;
}
__device__ __forceinline__ float sigm(float x) { return 1.0f / (1.0f + __expf(-x)); }
__device__ __forceinline__ float tanhf_(float x) { return 2.0f / (1.0f + __expf(-2.0f * x)) - 1.0f; }
// h = sigmoid(o) * tanh(sigmoid(i) * tanh(g))   (c_prev == 0, faithful to reference)
__device__ __forceinline__ float cellh(float i, float g, float o) {
  float c = sigm(i) * tanhf_(g);
  return sigm(o) * tanhf_(c);
}

__device__ __forceinline__ float ldG(const float* p, long i) { return p[i]; }
__device__ __forceinline__ float ldG(const unsigned short* p, long i) { return bf2f(p[i]); }
__device__ __forceinline__ void stG(float* p, long i, float v) { p[i] = v; }
__device__ __forceinline__ void stG(unsigned short* p, long i, float v) { p[i] = f2bf(v); }
__device__ __forceinline__ void ld2G(const float* p, long i, float& a, float& b) {
  float2 t = *(const float2*)(p + i); a = t.x; b = t.y;
}
__device__ __forceinline__ void ld2G(const unsigned short* p, long i, float& a, float& b) {
  unsigned u = *(const unsigned*)(p + i);
  a = bf2f((unsigned short)(u & 0xffffu)); b = bf2f((unsigned short)(u >> 16));
}

// ---------------------------------------------------------------------------
// prep: pack W_ih_{f,b} rows [i,g,o] -> bf16 [1536][320] (zero-pad K), biases
// ---------------------------------------------------------------------------
__global__ __launch_bounds__(256)
void prep_kernel(const float* __restrict__ Wf, const float* __restrict__ Wb,
                 const float* __restrict__ bihf, const float* __restrict__ bhhf,
                 const float* __restrict__ bihb, const float* __restrict__ bhhb,
                 unsigned short* __restrict__ Wfp, unsigned short* __restrict__ Wbp,
                 float* __restrict__ bpf, float* __restrict__ bpb) {
  const int t0 = blockIdx.x * blockDim.x + threadIdx.x;
  const int stride = gridDim.x * blockDim.x;
  const int tot = G3 * EP;
  for (int idx = t0; idx < tot; idx += stride) {
    const int n = idx / EP, k = idx - n * EP;
    const int src = (n < H_) ? n : n + H_;
    const float vf = (k < E_) ? Wf[(size_t)src * E_ + k] : 0.0f;
    const float vb = (k < E_) ? Wb[(size_t)src * E_ + k] : 0.0f;
    Wfp[idx] = f2bf(vf);
    Wbp[idx] = f2bf(vb);
  }
  for (int n = t0; n < G3; n += stride) {
    const int src = (n < H_) ? n : n + H_;
    bpf[n] = bihf[src] + bhhf[src];
    bpb[n] = bihb[src] + bhhb[src];
  }
}

// ---------------------------------------------------------------------------
// xstage: x = embed_table[inputs] -> bf16 [32768][320]
// ---------------------------------------------------------------------------
__global__ __launch_bounds__(256)
void xstage_kernel(const int* __restrict__ inp, const float* __restrict__ emb,
                   unsigned short* __restrict__ xbf) {
  const int t = blockIdx.x * blockDim.x + threadIdx.x;
  const int row = t / 80, q = t - row * 80;
  const int c0 = q * 4;
  const int vid = inp[row];
  unsigned short o[4];
#pragma unroll
  for (int e = 0; e < 4; ++e) {
    const int c = c0 + e;
    o[e] = (c < E_) ? f2bf(emb[(size_t)vid * E_ + c]) : (unsigned short)0;
  }
  uint2 pv;
  pv.x = (unsigned)o[0] | ((unsigned)o[1] << 16);
  pv.y = (unsigned)o[2] | ((unsigned)o[3] << 16);
  *(uint2*)&xbf[(size_t)row * EP + c0] = pv;
}

// ---------------------------------------------------------------------------
// GEMM 128x128 tile, BK=32, 4 waves, 16x16x32 MFMA (round-1-verified)
// ---------------------------------------------------------------------------
template<bool REMAP, typename GT>
__global__ __launch_bounds__(256)
void gemm_kernel(const unsigned short* __restrict__ A, const unsigned short* __restrict__ W,
                 const float* __restrict__ bias, GT* __restrict__ C) {
  __shared__ short lA[128 * 40];
  __shared__ short lB[128 * 40];
  const int tid = threadIdx.x;
  const int w = tid >> 6, l = tid & 63;
  const int wr = w >> 1, wc = w & 1;
  const int Mb = blockIdx.x * 128, Nb = blockIdx.y * 128;
  f32x4 acc[4][4];
#pragma unroll
  for (int i = 0; i < 4; ++i)
#pragma unroll
    for (int j = 0; j < 4; ++j) acc[i][j] = f32x4{0.f, 0.f, 0.f, 0.f};

  const int srow = tid >> 1, shalf = (tid & 1) * 16;
  for (int kk = 0; kk < EP; kk += 32) {
    const s16x8* ga = (const s16x8*)&A[(size_t)(Mb + srow) * EP + kk + shalf];
    const s16x8* gb = (const s16x8*)&W[(size_t)(Nb + srow) * EP + kk + shalf];
    s16x8 a0 = ga[0], a1 = ga[1], b0 = gb[0], b1 = gb[1];
    *(s16x8*)&lA[srow * 40 + shalf]     = a0;
    *(s16x8*)&lA[srow * 40 + shalf + 8] = a1;
    *(s16x8*)&lB[srow * 40 + shalf]     = b0;
    *(s16x8*)&lB[srow * 40 + shalf + 8] = b1;
    __syncthreads();
    s16x8 af[4], bf[4];
#pragma unroll
    for (int mt = 0; mt < 4; ++mt)
      af[mt] = *(const s16x8*)&lA[(wr * 64 + mt * 16 + (l & 15)) * 40 + 8 * (l >> 4)];
#pragma unroll
    for (int nt = 0; nt < 4; ++nt)
      bf[nt] = *(const s16x8*)&lB[(wc * 64 + nt * 16 + (l & 15)) * 40 + 8 * (l >> 4)];
#pragma unroll
    for (int mt = 0; mt < 4; ++mt)
#pragma unroll
      for (int nt = 0; nt < 4; ++nt)
        acc[mt][nt] = __builtin_amdgcn_mfma_f32_16x16x32_bf16(af[mt], bf[nt], acc[mt][nt], 0, 0, 0);
    __syncthreads();
  }
#pragma unroll
  for (int mt = 0; mt < 4; ++mt) {
#pragma unroll
    for (int nt = 0; nt < 4; ++nt) {
      const int gc = Nb + wc * 64 + nt * 16 + (l & 15);
      const float bv = bias[gc];
#pragma unroll
      for (int r = 0; r < 4; ++r) {
        const int gr = Mb + wr * 64 + mt * 16 + (l >> 4) * 4 + r;
        const int orow = REMAP ? (((gr & 511) << 6) | (gr >> 9)) : gr;
        stG(C, (long)orow * G3 + gc, acc[mt][nt][r] + bv);
      }
    }
  }
}

// ---------------------------------------------------------------------------
// cellmax pass 1: partial max over S-chunks (grid 64 x 8 -> 512 blocks)
// ---------------------------------------------------------------------------
template<typename GT>
__global__ __launch_bounds__(256)
void cellmax1_kernel(const GT* __restrict__ G, float* __restrict__ part) {
  const int b = blockIdx.x, ch = blockIdx.y, tid = threadIdx.x;
  const int j0 = tid * 2;
  float mx0 = -2.f, mx1 = -2.f;
#pragma unroll 1
  for (int s = ch * 64; s < ch * 64 + 64; ++s) {
    const long base = (long)(b * S_ + s) * G3;
    float i0, i1, g0, g1, o0, o1;
    ld2G(G, base + j0, i0, i1);
    ld2G(G, base + 512 + j0, g0, g1);
    ld2G(G, base + 1024 + j0, o0, o1);
    mx0 = fmaxf(mx0, cellh(i0, g0, o0));
    mx1 = fmaxf(mx1, cellh(i1, g1, o1));
  }
  part[(ch * 64 + b) * 512 + j0]     = mx0;
  part[(ch * 64 + b) * 512 + j0 + 1] = mx1;
}

__global__ __launch_bounds__(256)
void cellmax2_kernel(const float* __restrict__ part, float* __restrict__ out) {
  const int b = blockIdx.x, tid = threadIdx.x;
  const int j0 = tid * 2;
  float mx0 = -2.f, mx1 = -2.f;
#pragma unroll
  for (int ch = 0; ch < 8; ++ch) {
    const float2 v = *(const float2*)&part[(ch * 64 + b) * 512 + j0];
    mx0 = fmaxf(mx0, v.x);
    mx1 = fmaxf(mx1, v.y);
  }
  out[b * 1024 + j0] = mx0;
  out[b * 1024 + j0 + 1] = mx1;
}

// flags: [4 grp][16 rank] spaced 16 dwords (64B) = 1024 dwords
__global__ __launch_bounds__(256) void zero_sync_kernel(unsigned* p) {
  for (int i = threadIdx.x; i < 1024; i += 256) p[i] = 0;
}

// ---------------------------------------------------------------------------
// scan: backward LSTM, 512 sequential steps. 64 WGs = 4 groups x 16 WGs.
// Group = 16 batch rows; WG owns 96 gate rows, W_hh fragments in registers.
// Exchange via agent-scope atomics (round-1-proven primitives), slimmed:
// relaxed poll + one acquire fence; per-producer flags; x-gates consumed at
// the nonlinearity phase (pollers carry no outstanding loads at poll time).
// ---------------------------------------------------------------------------
template<typename GT>
__global__ __launch_bounds__(384, 1)
void scan_kernel(const float* __restrict__ Whh, const GT* __restrict__ Gb,
                 unsigned* __restrict__ hbuf, unsigned* __restrict__ flags,
                 float* __restrict__ out) {
  __shared__ __align__(16) unsigned hl[16 * 260];   // h as [16][520] bf16 (+pad)
  __shared__ float gbuf[6][16][20];

  const int tid = threadIdx.x;
  const int wv = tid >> 6, l = tid & 63;
  const int grp = blockIdx.x >> 4, rank = blockIdx.x & 15;
  const int jbase = rank * 32;

  // ---- one-time: W_hh fragments -> registers (16 x s16x8 = 64 VGPR/wave) ----
  const int myn = (wv >> 1) * 512 + (wv & 1) * 16 + jbase;
  const int nfrag = myn + (l & 15);
  const int nsrc = (nfrag < 512) ? nfrag : nfrag + 512;  // packed igo -> source row
  const float* wrow = Whh + (size_t)nsrc * 512 + 8 * (l >> 4);
  s16x8 wf[16];
#pragma unroll
  for (int kc = 0; kc < 16; ++kc) {
    const float4 v0 = *(const float4*)(wrow + kc * 32);
    const float4 v1 = *(const float4*)(wrow + kc * 32 + 4);
    s16x8 vv;
    vv[0] = (short)f2bf(v0.x); vv[1] = (short)f2bf(v0.y);
    vv[2] = (short)f2bf(v0.z); vv[3] = (short)f2bf(v0.w);
    vv[4] = (short)f2bf(v1.x); vv[5] = (short)f2bf(v1.y);
    vv[6] = (short)f2bf(v1.z); vv[7] = (short)f2bf(v1.w);
    wf[kc] = vv;
  }

  const int mrow = (l >> 4) * 4;      // MFMA C/D row base
  const int prow = tid >> 4;          // nonlin/publish row (tid<256)
  const int pc   = (tid & 15) * 2;    // nonlin/publish col pair
  const unsigned short* hls = (const unsigned short*)hl;
  float mx0 = -2.f, mx1 = -2.f;

#pragma unroll 1
  for (int t = S_ - 1; t >= 0; --t) {
    f32x4 a0 = {0,0,0,0}, a1 = {0,0,0,0}, a2 = {0,0,0,0}, a3 = {0,0,0,0};
    if (t != S_ - 1) {
      const unsigned seq = (unsigned)(S_ - 1 - t);
      // relaxed poll: 16 lanes of wave 0 watch 16 producer flags; no per-iter
      // fences, so detection latency is one LLC trip, not fence + trip.
      if (wv == 0) {
        const unsigned* fp = flags + (unsigned)(grp * 16 + (l & 15)) * 16;
        unsigned mine = seq;
        for (int it = 0; it < (1 << 16); ++it) {
          if (l < 16) mine = __hip_atomic_load(fp, __ATOMIC_RELAXED, __HIP_MEMORY_SCOPE_AGENT);
          if (__all((int)(mine >= seq))) break;
        }
      }
      __syncthreads();
      __builtin_amdgcn_fence(__ATOMIC_ACQUIRE, "agent");
    }
    // x-gates for this step: loaded by nonlin threads, consumed only after the
    // MFMA phase -> HBM latency hides under h-staging + MFMA.
    float xa0 = 0, xa1 = 0, xb0 = 0, xb1 = 0, xc0 = 0, xc1 = 0;
    if (tid < 256) {
      const long rowb = (long)(t * 64 + grp * 16 + prow) * G3 + (jbase + pc);
      ld2G(Gb, rowb,        xa0, xa1);
      ld2G(Gb, rowb + 512,  xb0, xb1);
      ld2G(Gb, rowb + 1024, xc0, xc1);
    }
    if (t != S_ - 1) {
      // stage group h (written at step t+1, slot (t+1)&1) -> LDS (16 KB)
      const u64* hs = (const u64*)&hbuf[(((t + 1) & 1) * 4 + grp) * 4096];
      for (int idx = tid; idx < 2048; idx += 384) {
        u64 v = __hip_atomic_load(hs + idx, __ATOMIC_RELAXED, __HIP_MEMORY_SCOPE_AGENT);
        *(u64*)&hl[(idx >> 7) * 260 + (idx & 127) * 2] = v;
      }
      __syncthreads();
      // gates = h @ Whh_slice^T  (W fragments in registers, 4 indep chains)
#pragma unroll
      for (int kc = 0; kc < 16; kc += 4) {
        s16x8 fa;
        fa = *(const s16x8*)&hls[(l & 15) * 520 + (kc + 0) * 32 + 8 * (l >> 4)];
        a0 = __builtin_amdgcn_mfma_f32_16x16x32_bf16(fa, wf[kc + 0], a0, 0, 0, 0);
        fa = *(const s16x8*)&hls[(l & 15) * 520 + (kc + 1) * 32 + 8 * (l >> 4)];
        a1 = __builtin_amdgcn_mfma_f32_16x16x32_bf16(fa, wf[kc + 1], a1, 0, 0, 0);
        fa = *(const s16x8*)&hls[(l & 15) * 520 + (kc + 2) * 32 + 8 * (l >> 4)];
        a2 = __builtin_amdgcn_mfma_f32_16x16x32_bf16(fa, wf[kc + 2], a2, 0, 0, 0);
        fa = *(const s16x8*)&hls[(l & 15) * 520 + (kc + 3) * 32 + 8 * (l >> 4)];
        a3 = __builtin_amdgcn_mfma_f32_16x16x32_bf16(fa, wf[kc + 3], a3, 0, 0, 0);
      }
    }
#pragma unroll
    for (int r = 0; r < 4; ++r)
      gbuf[wv][mrow + r][l & 15] = (a0[r] + a1[r]) + (a2[r] + a3[r]);
    __syncthreads();
    if (tid < 256) {
      const int tb = pc >> 4, c0 = pc & 15, c1 = c0 + 1;   // pc even: both in same tile
      const float h0 = cellh(gbuf[tb][prow][c0] + xa0,
                             gbuf[2 + tb][prow][c0] + xb0,
                             gbuf[4 + tb][prow][c0] + xc0);
      const float h1 = cellh(gbuf[tb][prow][c1] + xa1,
                             gbuf[2 + tb][prow][c1] + xb1,
                             gbuf[4 + tb][prow][c1] + xc1);
      mx0 = fmaxf(mx0, h0);
      mx1 = fmaxf(mx1, h1);
      if (t) {
        const unsigned pk = (unsigned)f2bf(h0) | ((unsigned)f2bf(h1) << 16);
        unsigned* dst = &hbuf[((t & 1) * 4 + grp) * 4096 + prow * 256 + (jbase >> 1) + (tid & 15)];
        __hip_atomic_store(dst, pk, __ATOMIC_RELAXED, __HIP_MEMORY_SCOPE_AGENT);
      }
    }
    __syncthreads();   // drains all memory ops -> h stores visible before flag
    if (t && tid == 0)
      __hip_atomic_store(&flags[(grp * 16 + rank) * 16], (unsigned)(S_ - t),
                         __ATOMIC_RELEASE, __HIP_MEMORY_SCOPE_AGENT);
  }
  if (tid < 256) {
    const int b = grp * 16 + prow;
    out[b * 1024 + 512 + jbase + pc]     = mx0;
    out[b * 1024 + 512 + jbase + pc + 1] = mx1;
  }
}

// ---------------------------------------------------------------------------
extern "C" void kernel_launch(void* const* d_in, const int* in_sizes, int n_in,
                              void* d_out, int out_size, void* d_ws, size_t ws_size,
                              hipStream_t stream) {
  const int*   inp  = (const int*)  d_in[0];
  const float* emb  = (const float*)d_in[1];
  const float* Wihf = (const float*)d_in[2];
  // d_in[3] = W_hh_f: unused (forward state is always zero)
  const float* bihf = (const float*)d_in[4];
  const float* bhhf = (const float*)d_in[5];
  const float* Wihb = (const float*)d_in[6];
  const float* Whhb = (const float*)d_in[7];
  const float* bihb = (const float*)d_in[8];
  const float* bhhb = (const float*)d_in[9];
  float* out = (float*)d_out;
  char* ws = (char*)d_ws;

  const size_t o_xbf  = 0;                        // 20971520
  const size_t o_Wfp  = o_xbf + 20971520;         // 983040
  const size_t o_Wbp  = o_Wfp + 983040;           // 983040
  const size_t o_bpf  = o_Wbp + 983040;           // 6144
  const size_t o_bpb  = o_bpf + 6144;             // 6144
  const size_t o_hbuf = o_bpb + 6144;             // 2*4*16*256*4 = 131072
  const size_t o_sync = o_hbuf + 131072;          // 1024 dwords = 4096
  const size_t o_part = o_sync + 4096;            // 8*64*512*4 = 1048576
  const size_t o_G    = o_part + 1048576;
  const size_t need_f32 = o_G + (size_t)32768 * G3 * 4;

  unsigned short* xbf = (unsigned short*)(ws + o_xbf);
  unsigned short* Wfp = (unsigned short*)(ws + o_Wfp);
  unsigned short* Wbp = (unsigned short*)(ws + o_Wbp);
  float* bpf = (float*)(ws + o_bpf);
  float* bpb = (float*)(ws + o_bpb);
  unsigned* hbuf = (unsigned*)(ws + o_hbuf);
  unsigned* flags = (unsigned*)(ws + o_sync);
  float* part = (float*)(ws + o_part);
  void* G = (void*)(ws + o_G);

  hipLaunchKernelGGL(prep_kernel, dim3(512), dim3(256), 0, stream,
                     Wihf, Wihb, bihf, bhhf, bihb, bhhb, Wfp, Wbp, bpf, bpb);
  hipLaunchKernelGGL(xstage_kernel, dim3(10240), dim3(256), 0, stream, inp, emb, xbf);
  hipLaunchKernelGGL(zero_sync_kernel, dim3(1), dim3(256), 0, stream, flags);

  if (ws_size >= need_f32) {
    float* Gbuf = (float*)G;
    // forward
    hipLaunchKernelGGL((gemm_kernel<false, float>), dim3(256, 12), dim3(256), 0, stream,
                       xbf, Wfp, bpf, Gbuf);
    hipLaunchKernelGGL((cellmax1_kernel<float>), dim3(64, 8), dim3(256), 0, stream, Gbuf, part);
    hipLaunchKernelGGL(cellmax2_kernel, dim3(64), dim3(256), 0, stream, part, out);
    // backward
    hipLaunchKernelGGL((gemm_kernel<true, float>), dim3(256, 12), dim3(256), 0, stream,
                       xbf, Wbp, bpb, Gbuf);
    hipLaunchKernelGGL((scan_kernel<float>), dim3(NWGS), dim3(384), 0, stream,
                       Whhb, Gbuf, hbuf, flags, out);
  } else {
    unsigned short* Gbuf = (unsigned short*)G;
    hipLaunchKernelGGL((gemm_kernel<false, unsigned short>), dim3(256, 12), dim3(256), 0, stream,
                       xbf, Wfp, bpf, Gbuf);
    hipLaunchKernelGGL((cellmax1_kernel<unsigned short>), dim3(64, 8), dim3(256), 0, stream, Gbuf, part);
    hipLaunchKernelGGL(cellmax2_kernel, dim3(64), dim3(256), 0, stream, part, out);
    hipLaunchKernelGGL((gemm_kernel<true, unsigned short>), dim3(256, 12), dim3(256), 0, stream,
                       xbf, Wbp, bpb, Gbuf);
    hipLaunchKernelGGL((scan_kernel<unsigned short>), dim3(NWGS), dim3(384), 0, stream,
                       Whhb, Gbuf, hbuf, flags, out);
  }
}

// Round 5
// 1755.921 us; speedup vs baseline: 1.7681x; 1.7681x over previous
//
#include <hip/hip_runtime.h>
#include <cstdint>
#include <cstddef>

// Problem dims
#define B_   64
#define S_   512
#define E_   300
#define EP   320     // E padded to multiple of 32 (zero pad)
#define H_   512
#define G3   1536    // packed gates: [i(512), g(512), o(512)] (f-gate unused: c_prev==0)
#define NWGS 64      // scan grid: 4 groups x 16 WGs

typedef float  f32x4 __attribute__((ext_vector_type(4)));
typedef short  s16x8 __attribute__((ext_vector_type(8)));
typedef unsigned long long u64;

__device__ __forceinline__ unsigned short f2bf(float f) {
  union { float f; unsigned u; } v; v.f = f;
  return (unsigned short)((v.u + 0x7fffu + ((v.u >> 16) & 1u)) >> 16);  // RNE
}
__device__ __forceinline__ float bf2f(unsigned short s) {
  union { unsigned u; float f; } v; v.u = ((unsigned)s) << 16;
  return v.f;
}
__device__ __forceinline__ float sigm(float x) { return 1.0f / (1.0f + __expf(-x)); }
__device__ __forceinline__ float tanhf_(float x) { return 2.0f / (1.0f + __expf(-2.0f * x)) - 1.0f; }
// h = sigmoid(o) * tanh(sigmoid(i) * tanh(g))   (c_prev == 0, faithful to reference)
__device__ __forceinline__ float cellh(float i, float g, float o) {
  float c = sigm(i) * tanhf_(g);
  return sigm(o) * tanhf_(c);
}

__device__ __forceinline__ float ldG(const float* p, long i) { return p[i]; }
__device__ __forceinline__ float ldG(const unsigned short* p, long i) { return bf2f(p[i]); }
__device__ __forceinline__ void stG(float* p, long i, float v) { p[i] = v; }
__device__ __forceinline__ void stG(unsigned short* p, long i, float v) { p[i] = f2bf(v); }
__device__ __forceinline__ void ld2G(const float* p, long i, float& a, float& b) {
  float2 t = *(const float2*)(p + i); a = t.x; b = t.y;
}
__device__ __forceinline__ void ld2G(const unsigned short* p, long i, float& a, float& b) {
  unsigned u = *(const unsigned*)(p + i);
  a = bf2f((unsigned short)(u & 0xffffu)); b = bf2f((unsigned short)(u >> 16));
}

// --- raw barriers (no vmcnt drain -> prefetches survive across them) ---
__device__ __forceinline__ void bar_lgkm() {
  asm volatile("s_waitcnt lgkmcnt(0)\ns_barrier" ::: "memory");
}
__device__ __forceinline__ void bar_only() {
  asm volatile("s_barrier" ::: "memory");
}

// ---------------------------------------------------------------------------
// prep: pack W_ih_{f,b} rows [i,g,o] -> bf16 [1536][320] (zero-pad K), biases
// ---------------------------------------------------------------------------
__global__ __launch_bounds__(256)
void prep_kernel(const float* __restrict__ Wf, const float* __restrict__ Wb,
                 const float* __restrict__ bihf, const float* __restrict__ bhhf,
                 const float* __restrict__ bihb, const float* __restrict__ bhhb,
                 unsigned short* __restrict__ Wfp, unsigned short* __restrict__ Wbp,
                 float* __restrict__ bpf, float* __restrict__ bpb) {
  const int t0 = blockIdx.x * blockDim.x + threadIdx.x;
  const int stride = gridDim.x * blockDim.x;
  const int tot = G3 * EP;
  for (int idx = t0; idx < tot; idx += stride) {
    const int n = idx / EP, k = idx - n * EP;
    const int src = (n < H_) ? n : n + H_;
    const float vf = (k < E_) ? Wf[(size_t)src * E_ + k] : 0.0f;
    const float vb = (k < E_) ? Wb[(size_t)src * E_ + k] : 0.0f;
    Wfp[idx] = f2bf(vf);
    Wbp[idx] = f2bf(vb);
  }
  for (int n = t0; n < G3; n += stride) {
    const int src = (n < H_) ? n : n + H_;
    bpf[n] = bihf[src] + bhhf[src];
    bpb[n] = bihb[src] + bhhb[src];
  }
}

// ---------------------------------------------------------------------------
// xstage: x = embed_table[inputs] -> bf16 [32768][320]
// ---------------------------------------------------------------------------
__global__ __launch_bounds__(256)
void xstage_kernel(const int* __restrict__ inp, const float* __restrict__ emb,
                   unsigned short* __restrict__ xbf) {
  const int t = blockIdx.x * blockDim.x + threadIdx.x;
  const int row = t / 80, q = t - row * 80;
  const int c0 = q * 4;
  const int vid = inp[row];
  unsigned short o[4];
#pragma unroll
  for (int e = 0; e < 4; ++e) {
    const int c = c0 + e;
    o[e] = (c < E_) ? f2bf(emb[(size_t)vid * E_ + c]) : (unsigned short)0;
  }
  uint2 pv;
  pv.x = (unsigned)o[0] | ((unsigned)o[1] << 16);
  pv.y = (unsigned)o[2] | ((unsigned)o[3] << 16);
  *(uint2*)&xbf[(size_t)row * EP + c0] = pv;
}

// ---------------------------------------------------------------------------
// GEMM 128x128 tile, BK=32, 4 waves, 16x16x32 MFMA (round-1-verified)
// ---------------------------------------------------------------------------
template<bool REMAP, typename GT>
__global__ __launch_bounds__(256)
void gemm_kernel(const unsigned short* __restrict__ A, const unsigned short* __restrict__ W,
                 const float* __restrict__ bias, GT* __restrict__ C) {
  __shared__ short lA[128 * 40];
  __shared__ short lB[128 * 40];
  const int tid = threadIdx.x;
  const int w = tid >> 6, l = tid & 63;
  const int wr = w >> 1, wc = w & 1;
  const int Mb = blockIdx.x * 128, Nb = blockIdx.y * 128;
  f32x4 acc[4][4];
#pragma unroll
  for (int i = 0; i < 4; ++i)
#pragma unroll
    for (int j = 0; j < 4; ++j) acc[i][j] = f32x4{0.f, 0.f, 0.f, 0.f};

  const int srow = tid >> 1, shalf = (tid & 1) * 16;
  for (int kk = 0; kk < EP; kk += 32) {
    const s16x8* ga = (const s16x8*)&A[(size_t)(Mb + srow) * EP + kk + shalf];
    const s16x8* gb = (const s16x8*)&W[(size_t)(Nb + srow) * EP + kk + shalf];
    s16x8 a0 = ga[0], a1 = ga[1], b0 = gb[0], b1 = gb[1];
    *(s16x8*)&lA[srow * 40 + shalf]     = a0;
    *(s16x8*)&lA[srow * 40 + shalf + 8] = a1;
    *(s16x8*)&lB[srow * 40 + shalf]     = b0;
    *(s16x8*)&lB[srow * 40 + shalf + 8] = b1;
    __syncthreads();
    s16x8 af[4], bf[4];
#pragma unroll
    for (int mt = 0; mt < 4; ++mt)
      af[mt] = *(const s16x8*)&lA[(wr * 64 + mt * 16 + (l & 15)) * 40 + 8 * (l >> 4)];
#pragma unroll
    for (int nt = 0; nt < 4; ++nt)
      bf[nt] = *(const s16x8*)&lB[(wc * 64 + nt * 16 + (l & 15)) * 40 + 8 * (l >> 4)];
#pragma unroll
    for (int mt = 0; mt < 4; ++mt)
#pragma unroll
      for (int nt = 0; nt < 4; ++nt)
        acc[mt][nt] = __builtin_amdgcn_mfma_f32_16x16x32_bf16(af[mt], bf[nt], acc[mt][nt], 0, 0, 0);
    __syncthreads();
  }
#pragma unroll
  for (int mt = 0; mt < 4; ++mt) {
#pragma unroll
    for (int nt = 0; nt < 4; ++nt) {
      const int gc = Nb + wc * 64 + nt * 16 + (l & 15);
      const float bv = bias[gc];
#pragma unroll
      for (int r = 0; r < 4; ++r) {
        const int gr = Mb + wr * 64 + mt * 16 + (l >> 4) * 4 + r;
        const int orow = REMAP ? (((gr & 511) << 6) | (gr >> 9)) : gr;
        stG(C, (long)orow * G3 + gc, acc[mt][nt][r] + bv);
      }
    }
  }
}

// ---------------------------------------------------------------------------
// cellmax pass 1/2 (forward half)
// ---------------------------------------------------------------------------
template<typename GT>
__global__ __launch_bounds__(256)
void cellmax1_kernel(const GT* __restrict__ G, float* __restrict__ part) {
  const int b = blockIdx.x, ch = blockIdx.y, tid = threadIdx.x;
  const int j0 = tid * 2;
  float mx0 = -2.f, mx1 = -2.f;
#pragma unroll 1
  for (int s = ch * 64; s < ch * 64 + 64; ++s) {
    const long base = (long)(b * S_ + s) * G3;
    float i0, i1, g0, g1, o0, o1;
    ld2G(G, base + j0, i0, i1);
    ld2G(G, base + 512 + j0, g0, g1);
    ld2G(G, base + 1024 + j0, o0, o1);
    mx0 = fmaxf(mx0, cellh(i0, g0, o0));
    mx1 = fmaxf(mx1, cellh(i1, g1, o1));
  }
  part[(ch * 64 + b) * 512 + j0]     = mx0;
  part[(ch * 64 + b) * 512 + j0 + 1] = mx1;
}

__global__ __launch_bounds__(256)
void cellmax2_kernel(const float* __restrict__ part, float* __restrict__ out) {
  const int b = blockIdx.x, tid = threadIdx.x;
  const int j0 = tid * 2;
  float mx0 = -2.f, mx1 = -2.f;
#pragma unroll
  for (int ch = 0; ch < 8; ++ch) {
    const float2 v = *(const float2*)&part[(ch * 64 + b) * 512 + j0];
    mx0 = fmaxf(mx0, v.x);
    mx1 = fmaxf(mx1, v.y);
  }
  out[b * 1024 + j0] = mx0;
  out[b * 1024 + j0 + 1] = mx1;
}

// flags: [4 grp][16 rank] spaced 16 dwords (64B) = 1024 dwords
__global__ __launch_bounds__(256) void zero_sync_kernel(unsigned* p) {
  for (int i = threadIdx.x; i < 1024; i += 256) p[i] = 0;
}

// ---------------------------------------------------------------------------
// scan: backward LSTM, 512 sequential steps. 64 WGs = 4 groups x 16 WGs.
// Fence-free LLC protocol: publishes via global_atomic_swap (execute at the
// device coherence point), reads via sc0 sc1 loads (bypass L1+L2, read LLC).
// No acquire/release fences -> no per-step L2 flash-invalidate -> x-gates
// stay L2-cached and are prefetched 1 step ahead across raw s_barriers.
// Wave roles: w0 polls (no prefetch in flight); w1-4 nonlin/publish/prefetch;
// all waves h-stage (tid<256) + MFMA.
// ---------------------------------------------------------------------------
template<typename GT>
__global__ __launch_bounds__(384, 1)
void scan_kernel(const float* __restrict__ Whh, const GT* __restrict__ Gb,
                 unsigned* __restrict__ hbuf, unsigned* __restrict__ flags,
                 float* __restrict__ out) {
  __shared__ __align__(16) unsigned hl[16 * 260];   // h as [16][520] bf16 (+pad)
  __shared__ float gbuf[6][16][20];

  const int tid = threadIdx.x;
  const int wv = tid >> 6, l = tid & 63;
  const int grp = blockIdx.x >> 4, rank = blockIdx.x & 15;
  const int jbase = rank * 32;

  // ---- one-time: W_hh fragments -> registers (16 x s16x8 = 64 VGPR/wave) ----
  const int myn = (wv >> 1) * 512 + (wv & 1) * 16 + jbase;
  const int nfrag = myn + (l & 15);
  const int nsrc = (nfrag < 512) ? nfrag : nfrag + 512;  // packed igo -> source row
  const float* wrow = Whh + (size_t)nsrc * 512 + 8 * (l >> 4);
  s16x8 wf[16];
#pragma unroll
  for (int kc = 0; kc < 16; ++kc) {
    const float4 v0 = *(const float4*)(wrow + kc * 32);
    const float4 v1 = *(const float4*)(wrow + kc * 32 + 4);
    s16x8 vv;
    vv[0] = (short)f2bf(v0.x); vv[1] = (short)f2bf(v0.y);
    vv[2] = (short)f2bf(v0.z); vv[3] = (short)f2bf(v0.w);
    vv[4] = (short)f2bf(v1.x); vv[5] = (short)f2bf(v1.y);
    vv[6] = (short)f2bf(v1.z); vv[7] = (short)f2bf(v1.w);
    wf[kc] = vv;
  }

  const int mrow = (l >> 4) * 4;          // MFMA C/D row base
  const int slot = tid - 64;              // nonlin slot for waves 1-4
  const bool nl  = (slot >= 0 && slot < 256);
  const int prow = nl ? (slot >> 4) : 0;  // nonlin row
  const int pc   = (slot & 15) * 2;       // nonlin col pair
  const unsigned short* hls = (const unsigned short*)hl;
  float mx0 = -2.f, mx1 = -2.f;

  // x prefetch for t = S-1 (waves 1-4; stays in flight until first nonlin)
  float2 xa = {0, 0}, xb = {0, 0}, xc = {0, 0};
  if (nl) {
    const float2* xp = (const float2*)(Gb + (long)((S_ - 1) * 64 + grp * 16 + prow) * G3
                                          + (jbase + pc));
    xa = xp[0]; xb = xp[256]; xc = xp[512];   // +512, +1024 floats
  }

  __syncthreads();   // cover W-frag loads & first-use ordering

#pragma unroll 1
  for (int t = S_ - 1; t >= 0; --t) {
    // ---- phase P: wave 0 polls 16 producer flags (sc0 sc1 -> LLC) ----
    if (t != S_ - 1 && wv == 0) {
      const unsigned seq = (unsigned)(S_ - 1 - t);
      const unsigned* fp = flags + (unsigned)(grp * 16 + (l & 15)) * 16;
      unsigned mine = seq;
      for (int it = 0; it < (1 << 16); ++it) {
        if (l < 16) {
          unsigned v;
          asm volatile("global_load_dword %0, %1, off sc0 sc1\ns_waitcnt vmcnt(0)"
                       : "=v"(v) : "v"(fp) : "memory");
          mine = v;
        }
        if (__all((int)(mine >= seq))) break;
      }
    }
    bar_only();   // #1: release consumers (raw: prefetches stay in flight)

    // ---- phase H: stage group h (slot (t+1)&1) -> LDS, 2048 u64 by tid<256 ----
    if (t != S_ - 1 && tid < 256) {
      const u64* hs = (const u64*)&hbuf[(((t + 1) & 1) * 4 + grp) * 4096];
      const u64 *p0 = hs + tid,        *p1 = hs + tid + 256,
                *p2 = hs + tid + 512,  *p3 = hs + tid + 768,
                *p4 = hs + tid + 1024, *p5 = hs + tid + 1280,
                *p6 = hs + tid + 1536, *p7 = hs + tid + 1792;
      u64 v0, v1, v2, v3, v4, v5, v6, v7;
      asm volatile(
        "global_load_dwordx2 %0, %8, off sc0 sc1\n\t"
        "global_load_dwordx2 %1, %9, off sc0 sc1\n\t"
        "global_load_dwordx2 %2, %10, off sc0 sc1\n\t"
        "global_load_dwordx2 %3, %11, off sc0 sc1\n\t"
        "global_load_dwordx2 %4, %12, off sc0 sc1\n\t"
        "global_load_dwordx2 %5, %13, off sc0 sc1\n\t"
        "global_load_dwordx2 %6, %14, off sc0 sc1\n\t"
        "global_load_dwordx2 %7, %15, off sc0 sc1\n\t"
        "s_waitcnt vmcnt(0)"
        : "=&v"(v0), "=&v"(v1), "=&v"(v2), "=&v"(v3),
          "=&v"(v4), "=&v"(v5), "=&v"(v6), "=&v"(v7)
        : "v"(p0), "v"(p1), "v"(p2), "v"(p3), "v"(p4), "v"(p5), "v"(p6), "v"(p7)
        : "memory");
      const int i0 = tid;
      *(u64*)&hl[((i0)        >> 7) * 260 + (((i0)        & 127) * 2)] = v0;
      *(u64*)&hl[((i0 + 256)  >> 7) * 260 + (((i0 + 256)  & 127) * 2)] = v1;
      *(u64*)&hl[((i0 + 512)  >> 7) * 260 + (((i0 + 512)  & 127) * 2)] = v2;
      *(u64*)&hl[((i0 + 768)  >> 7) * 260 + (((i0 + 768)  & 127) * 2)] = v3;
      *(u64*)&hl[((i0 + 1024) >> 7) * 260 + (((i0 + 1024) & 127) * 2)] = v4;
      *(u64*)&hl[((i0 + 1280) >> 7) * 260 + (((i0 + 1280) & 127) * 2)] = v5;
      *(u64*)&hl[((i0 + 1536) >> 7) * 260 + (((i0 + 1536) & 127) * 2)] = v6;
      *(u64*)&hl[((i0 + 1792) >> 7) * 260 + (((i0 + 1792) & 127) * 2)] = v7;
    }
    bar_lgkm();   // #2: hl visible

    // ---- phase M: gates = h @ Whh^T (W fragments in registers) ----
    f32x4 a0 = {0,0,0,0}, a1 = {0,0,0,0}, a2 = {0,0,0,0}, a3 = {0,0,0,0};
    if (t != S_ - 1) {
#pragma unroll
      for (int kc = 0; kc < 16; kc += 4) {
        s16x8 fa;
        fa = *(const s16x8*)&hls[(l & 15) * 520 + (kc + 0) * 32 + 8 * (l >> 4)];
        a0 = __builtin_amdgcn_mfma_f32_16x16x32_bf16(fa, wf[kc + 0], a0, 0, 0, 0);
        fa = *(const s16x8*)&hls[(l & 15) * 520 + (kc + 1) * 32 + 8 * (l >> 4)];
        a1 = __builtin_amdgcn_mfma_f32_16x16x32_bf16(fa, wf[kc + 1], a1, 0, 0, 0);
        fa = *(const s16x8*)&hls[(l & 15) * 520 + (kc + 2) * 32 + 8 * (l >> 4)];
        a2 = __builtin_amdgcn_mfma_f32_16x16x32_bf16(fa, wf[kc + 2], a2, 0, 0, 0);
        fa = *(const s16x8*)&hls[(l & 15) * 520 + (kc + 3) * 32 + 8 * (l >> 4)];
        a3 = __builtin_amdgcn_mfma_f32_16x16x32_bf16(fa, wf[kc + 3], a3, 0, 0, 0);
      }
    }
#pragma unroll
    for (int r = 0; r < 4; ++r)
      gbuf[wv][mrow + r][l & 15] = (a0[r] + a1[r]) + (a2[r] + a3[r]);
    bar_lgkm();   // #3: gbuf visible

    // ---- phase N: nonlin + max + publish (waves 1-4) ----
    if (nl) {
      const int tb = pc >> 4, c0 = pc & 15, c1 = c0 + 1;
      const float h0 = cellh(gbuf[tb][prow][c0] + xa.x,
                             gbuf[2 + tb][prow][c0] + xb.x,
                             gbuf[4 + tb][prow][c0] + xc.x);
      const float h1 = cellh(gbuf[tb][prow][c1] + xa.y,
                             gbuf[2 + tb][prow][c1] + xb.y,
                             gbuf[4 + tb][prow][c1] + xc.y);
      mx0 = fmaxf(mx0, h0);
      mx1 = fmaxf(mx1, h1);
      if (t) {
        const unsigned pk = (unsigned)f2bf(h0) | ((unsigned)f2bf(h1) << 16);
        unsigned* dst = &hbuf[((t & 1) * 4 + grp) * 4096 + prow * 256 + (jbase >> 1) + (slot & 15)];
        asm volatile("global_atomic_swap %0, %1, off" :: "v"(dst), "v"(pk) : "memory");
        // prefetch next step's x-gates (plain cached loads; stay in flight)
        const float2* xp = (const float2*)(Gb + (long)((t - 1) * 64 + grp * 16 + prow) * G3
                                              + (jbase + pc));
        xa = xp[0]; xb = xp[256]; xc = xp[512];
        // wait only the swap's LLC ack (oldest); x loads keep flying
        asm volatile("s_waitcnt vmcnt(3)" ::: "memory");
      }
    }
    bar_only();   // #4: all swaps ack'd group-wide
    if (t && tid == 64) {
      unsigned* fp = &flags[(grp * 16 + rank) * 16];
      const unsigned sv = (unsigned)(S_ - t);
      asm volatile("global_atomic_swap %0, %1, off" :: "v"(fp), "v"(sv) : "memory");
    }
  }
  if (nl) {
    const int b = grp * 16 + prow;
    out[b * 1024 + 512 + jbase + pc]     = mx0;
    out[b * 1024 + 512 + jbase + pc + 1] = mx1;
  }
}

// ---------------------------------------------------------------------------
extern "C" void kernel_launch(void* const* d_in, const int* in_sizes, int n_in,
                              void* d_out, int out_size, void* d_ws, size_t ws_size,
                              hipStream_t stream) {
  const int*   inp  = (const int*)  d_in[0];
  const float* emb  = (const float*)d_in[1];
  const float* Wihf = (const float*)d_in[2];
  // d_in[3] = W_hh_f: unused (forward state is always zero)
  const float* bihf = (const float*)d_in[4];
  const float* bhhf = (const float*)d_in[5];
  const float* Wihb = (const float*)d_in[6];
  const float* Whhb = (const float*)d_in[7];
  const float* bihb = (const float*)d_in[8];
  const float* bhhb = (const float*)d_in[9];
  float* out = (float*)d_out;
  char* ws = (char*)d_ws;

  const size_t o_xbf  = 0;                        // 20971520
  const size_t o_Wfp  = o_xbf + 20971520;         // 983040
  const size_t o_Wbp  = o_Wfp + 983040;           // 983040
  const size_t o_bpf  = o_Wbp + 983040;           // 6144
  const size_t o_bpb  = o_bpf + 6144;             // 6144
  const size_t o_hbuf = o_bpb + 6144;             // 2*4*16*256*4 = 131072
  const size_t o_sync = o_hbuf + 131072;          // 1024 dwords = 4096
  const size_t o_part = o_sync + 4096;            // 8*64*512*4 = 1048576
  const size_t o_G    = o_part + 1048576;
  const size_t need_f32 = o_G + (size_t)32768 * G3 * 4;

  unsigned short* xbf = (unsigned short*)(ws + o_xbf);
  unsigned short* Wfp = (unsigned short*)(ws + o_Wfp);
  unsigned short* Wbp = (unsigned short*)(ws + o_Wbp);
  float* bpf = (float*)(ws + o_bpf);
  float* bpb = (float*)(ws + o_bpb);
  unsigned* hbuf = (unsigned*)(ws + o_hbuf);
  unsigned* flags = (unsigned*)(ws + o_sync);
  float* part = (float*)(ws + o_part);
  void* G = (void*)(ws + o_G);

  hipLaunchKernelGGL(prep_kernel, dim3(512), dim3(256), 0, stream,
                     Wihf, Wihb, bihf, bhhf, bihb, bhhb, Wfp, Wbp, bpf, bpb);
  hipLaunchKernelGGL(xstage_kernel, dim3(10240), dim3(256), 0, stream, inp, emb, xbf);
  hipLaunchKernelGGL(zero_sync_kernel, dim3(1), dim3(256), 0, stream, flags);

  if (ws_size >= need_f32) {
    float* Gbuf = (float*)G;
    // forward
    hipLaunchKernelGGL((gemm_kernel<false, float>), dim3(256, 12), dim3(256), 0, stream,
                       xbf, Wfp, bpf, Gbuf);
    hipLaunchKernelGGL((cellmax1_kernel<float>), dim3(64, 8), dim3(256), 0, stream, Gbuf, part);
    hipLaunchKernelGGL(cellmax2_kernel, dim3(64), dim3(256), 0, stream, part, out);
    // backward
    hipLaunchKernelGGL((gemm_kernel<true, float>), dim3(256, 12), dim3(256), 0, stream,
                       xbf, Wbp, bpb, Gbuf);
    hipLaunchKernelGGL((scan_kernel<float>), dim3(NWGS), dim3(384), 0, stream,
                       Whhb, Gbuf, hbuf, flags, out);
  } else {
    unsigned short* Gbuf = (unsigned short*)G;
    hipLaunchKernelGGL((gemm_kernel<false, unsigned short>), dim3(256, 12), dim3(256), 0, stream,
                       xbf, Wfp, bpf, Gbuf);
    hipLaunchKernelGGL((cellmax1_kernel<unsigned short>), dim3(64, 8), dim3(256), 0, stream, Gbuf, part);
    hipLaunchKernelGGL(cellmax2_kernel, dim3(64), dim3(256), 0, stream, part, out);
    hipLaunchKernelGGL((gemm_kernel<true, unsigned short>), dim3(256, 12), dim3(256), 0, stream,
                       xbf, Wbp, bpb, Gbuf);
    hipLaunchKernelGGL((scan_kernel<unsigned short>), dim3(NWGS), dim3(384), 0, stream,
                       Whhb, Gbuf, hbuf, flags, out);
  }
}